// Round 1
// baseline (218.917 us; speedup 1.0000x reference)
//
#include <hip/hip_runtime.h>

// Problem constants
constexpr int BATCH = 64;     // M
constexpr int IC    = 8192;   // K
constexpr int OC    = 8192;   // N
constexpr int OCH   = 4096;   // packed rows (OC/2)
constexpr int KSPLIT = 4;
constexpr int KPER  = IC / KSPLIT;   // 2048
constexpr int BK    = 64;            // K-chunk staged in LDS
constexpr int LDK   = BK + 8;        // padded LDS leading dim (72 elems = 144 B, 16B-aligned)

typedef __bf16 bf16x8 __attribute__((ext_vector_type(8)));
typedef float  f32x4  __attribute__((ext_vector_type(4)));

// fp32 -> bf16 with round-to-nearest-even (inputs are finite normals)
static __device__ __forceinline__ unsigned short f2bf(float f) {
    unsigned u = __float_as_uint(f);
    u += 0x7FFFu + ((u >> 16) & 1u);
    return (unsigned short)(u >> 16);
}

// exact bf16 encoding of small non-negative int (0..15): truncation is exact
static __device__ __forceinline__ unsigned short ibf(int n) {
    return (unsigned short)(__float_as_uint((float)n) >> 16);
}

// ---------------------------------------------------------------------------
// Prep: input fp32 [64,8192] -> bf16 in ws, plus per-row sums S[64]
// ---------------------------------------------------------------------------
__global__ __launch_bounds__(256) void prep_kernel(
    const float* __restrict__ in, unsigned short* __restrict__ Abf,
    float* __restrict__ S)
{
    const int b = blockIdx.x;
    const int t = threadIdx.x;
    const float* row = in + (size_t)b * IC;
    unsigned short* orow = Abf + (size_t)b * IC;

    float sum = 0.f;
#pragma unroll
    for (int i = 0; i < IC / 1024; ++i) {
        const int c = i * 1024 + t * 4;
        const float4 v = *(const float4*)(row + c);
        sum += (v.x + v.y) + (v.z + v.w);
        ushort4 o = make_ushort4(f2bf(v.x), f2bf(v.y), f2bf(v.z), f2bf(v.w));
        *(ushort4*)(orow + c) = o;
    }
#pragma unroll
    for (int off = 32; off > 0; off >>= 1) sum += __shfl_down(sum, off);

    __shared__ float red[4];
    if ((t & 63) == 0) red[t >> 6] = sum;
    __syncthreads();
    if (t == 0) S[b] = (red[0] + red[1]) + (red[2] + red[3]);
}

// ---------------------------------------------------------------------------
// GEMM: C[64, 8192] += delta*(A·Q^T) with affine constant folded per split.
// Block: 256 thr / 4 waves. Tile: M=64 x N=64 channels = lo+hi nibbles of the
// same 32 packed rows (each int32 read once, feeds 2 channels).
// Wave w: channels lW-rows [w*16, w*16+16); computes 4 m-tiles of 16x16.
// ---------------------------------------------------------------------------
__global__ __launch_bounds__(256) void gemm_kernel(
    const unsigned short* __restrict__ Abf,   // bf16 [64][8192]
    const int* __restrict__ wp,               // packed [4096][8192]
    const float* __restrict__ delta,
    const float* __restrict__ zp,
    const float* __restrict__ bias,
    const float* __restrict__ S,              // [64]
    float* __restrict__ out)                  // fp32 [64][8192], pre-zeroed
{
    __shared__ unsigned short lA[64 * LDK];   // A bf16 tile
    __shared__ unsigned short lW[64 * LDK];   // rows 0..31 = lo nibble, 32..63 = hi

    const int t    = threadIdx.x;
    const int wave = t >> 6;
    const int lane = t & 63;
    const int lm   = lane & 15;
    const int lq   = lane >> 4;

    const int nt = blockIdx.x & 127;      // 128 n-tiles
    const int ks = blockIdx.x >> 7;       // KSPLIT splits
    const int r0 = nt * 32;               // packed-row base
    const int kb0 = ks * KPER;

    f32x4 acc[4];
    const f32x4 zero4 = {0.f, 0.f, 0.f, 0.f};
#pragma unroll
    for (int i = 0; i < 4; ++i) acc[i] = zero4;

    // staging index split
    const int uAr = t >> 3, uAs = t & 7;      // A: 32 rows x 8 segs (x2)
    const int uWr = t >> 4, uWs = t & 15;     // W: 16 rows x 16 segs (x2)

    for (int kk = 0; kk < KPER; kk += BK) {
        const int kb = kb0 + kk;
        // issue global loads before the barrier (overlap with prev compute)
        const int4 a0 = *(const int4*)(Abf + (size_t)uAr        * IC + kb + uAs * 8);
        const int4 a1 = *(const int4*)(Abf + (size_t)(uAr + 32) * IC + kb + uAs * 8);
        const int4 w0 = *(const int4*)(wp  + (size_t)(r0 + uWr)      * IC + kb + uWs * 4);
        const int4 w1 = *(const int4*)(wp  + (size_t)(r0 + uWr + 16) * IC + kb + uWs * 4);

        __syncthreads();   // previous iteration's LDS reads complete

        *(int4*)(&lA[uAr        * LDK + uAs * 8]) = a0;
        *(int4*)(&lA[(uAr + 32) * LDK + uAs * 8]) = a1;

        {
            ushort4 lo = make_ushort4(ibf(w0.x & 15), ibf(w0.y & 15),
                                      ibf(w0.z & 15), ibf(w0.w & 15));
            ushort4 hi = make_ushort4(ibf((w0.x >> 4) & 15), ibf((w0.y >> 4) & 15),
                                      ibf((w0.z >> 4) & 15), ibf((w0.w >> 4) & 15));
            *(ushort4*)(&lW[uWr        * LDK + uWs * 4]) = lo;
            *(ushort4*)(&lW[(uWr + 32) * LDK + uWs * 4]) = hi;
        }
        {
            ushort4 lo = make_ushort4(ibf(w1.x & 15), ibf(w1.y & 15),
                                      ibf(w1.z & 15), ibf(w1.w & 15));
            ushort4 hi = make_ushort4(ibf((w1.x >> 4) & 15), ibf((w1.y >> 4) & 15),
                                      ibf((w1.z >> 4) & 15), ibf((w1.w >> 4) & 15));
            *(ushort4*)(&lW[(uWr + 16) * LDK + uWs * 4]) = lo;
            *(ushort4*)(&lW[(uWr + 48) * LDK + uWs * 4]) = hi;
        }

        __syncthreads();

#pragma unroll
        for (int s = 0; s < 2; ++s) {
            const int kc = s * 32 + lq * 8;
            const bf16x8 bfrg = *(const bf16x8*)(&lW[(wave * 16 + lm) * LDK + kc]);
#pragma unroll
            for (int mt = 0; mt < 4; ++mt) {
                const bf16x8 afrg = *(const bf16x8*)(&lA[(mt * 16 + lm) * LDK + kc]);
                acc[mt] = __builtin_amdgcn_mfma_f32_16x16x32_bf16(afrg, bfrg, acc[mt], 0, 0, 0);
            }
        }
    }

    // Epilogue: C/D layout col = lane&15 (n), row = lq*4 + reg (m within tile)
    const int cr = wave * 16 + lm;                        // lW row = channel-in-tile
    const int ch = (cr < 32) ? (r0 + cr) : (OCH + r0 + (cr - 32));
    const float d  = delta[ch];
    const float dz = d * zp[ch];
    const float bi = bias[ch];
    constexpr float inv_split = 1.f / (float)KSPLIT;

#pragma unroll
    for (int mt = 0; mt < 4; ++mt) {
#pragma unroll
        for (int r = 0; r < 4; ++r) {
            const int m = mt * 16 + lq * 4 + r;
            const float res = d * acc[mt][r] + (bi - dz * S[m]) * inv_split;
            atomicAdd(out + (size_t)m * OC + ch, res);
        }
    }
}

extern "C" void kernel_launch(void* const* d_in, const int* in_sizes, int n_in,
                              void* d_out, int out_size, void* d_ws, size_t ws_size,
                              hipStream_t stream) {
    const float* input = (const float*)d_in[0];
    const int*   wpk   = (const int*)d_in[1];
    const float* delta = (const float*)d_in[2];
    const float* zp    = (const float*)d_in[3];
    const float* bias  = (const float*)d_in[4];
    float* out = (float*)d_out;

    unsigned short* Abf = (unsigned short*)d_ws;                      // 1 MiB bf16 A
    float* S = (float*)((char*)d_ws + (size_t)BATCH * IC * 2);        // 64 floats

    // d_out is poisoned before every launch; atomics need zero-init.
    hipMemsetAsync(d_out, 0, (size_t)out_size * sizeof(float), stream);
    prep_kernel<<<dim3(BATCH), dim3(256), 0, stream>>>(input, Abf, S);
    gemm_kernel<<<dim3(128 * KSPLIT), dim3(256), 0, stream>>>(Abf, wpk, delta, zp, bias, S, out);
}